// Round 4
// baseline (286.719 us; speedup 1.0000x reference)
//
#include <hip/hip_runtime.h>
#include <hip/hip_bf16.h>
#include <math.h>

typedef _Float16 f16;
typedef _Float16 f16x8 __attribute__((ext_vector_type(8)));
typedef _Float16 f16x4 __attribute__((ext_vector_type(4)));
typedef float f32x4 __attribute__((ext_vector_type(4)));

#define MFMA(a, b, c) __builtin_amdgcn_mfma_f32_16x16x32_f16((a), (b), (c), 0, 0, 0)

constexpr int Dd = 64;
constexpr int Hh = 128;
constexpr int Nn = 4096;
constexpr int NT = 32;
constexpr float SLP = 0.2f;
constexpr float INV2K = 1.0f / 2048.0f;

// Per-d f16 layout in d_ws (preprocessed):
//   [0,8192)       W1 hi  [128][64] swzK64 image (LDS-ready)
//   [8192,16384)   W1 lo  fragment-linear (KC=2), direct VMEM reads
//   [16384,32768)  W2 hi  [128][128] swz image
//   [32768,49152)  W2 lo  fragment-linear (KC=4)
//   [49152,65536)  W3 hi
//   [65536,81920)  W3 lo
constexpr int PD = 81920;
constexpr size_t W1L_OFF = (size_t)Dd * PD * 2;  // bytes; then w1last f32[64][128]
constexpr size_t WS_NEEDED = W1L_OFF + (size_t)Dd * Hh * 4;

// XOR swizzle, [r][128] f16, 8-elem chunks, chunk ^= r&15
__device__ __forceinline__ int swz(int r, int c) {
  return (r << 7) + ((((c >> 3) ^ (r & 15)) << 3) | (c & 7));
}
// K=64 swizzle, [r][64] f16, chunk ^= r&7
__device__ __forceinline__ int swzK64(int r, int c) {
  return (r << 6) + (((((c >> 3) ^ r) & 7) << 3) | (c & 7));
}
// f32 overlay swizzle, [n][128] f32, 4-elem chunks
__device__ __forceinline__ int swzF(int n, int h) {
  return (n << 7) + ((((h >> 2) ^ n) & 31) << 2) + (h & 3);
}

struct HL { f16 h, l; };
__device__ __forceinline__ HL split(float v) {
  HL r;
  r.h = (f16)v;
  r.l = (f16)((v - (float)r.h) * 2048.0f);
  return r;
}

// Async contiguous global->LDS; nbytes multiple of 4096 (256 thr x 16B)
__device__ __forceinline__ void cp_lds_async(const void* g, void* l, int nbytes, int tid) {
  const int lane = tid & 63, wv = tid >> 6;
  for (int base = wv * 1024; base < nbytes; base += 4096) {
    __builtin_amdgcn_global_load_lds(
        (const __attribute__((address_space(1))) void*)((const char*)g + base + lane * 16),
        (__attribute__((address_space(3))) void*)((char*)l + base), 16, 0, 0);
  }
}

// ---------------- preprocess (output-coalesced 16B writes) -------------------
__global__ __launch_bounds__(256)
void prep_kernel(const float* __restrict__ W1, const float* __restrict__ W2,
                 const float* __restrict__ W3, f16* __restrict__ wsf,
                 float* __restrict__ w1lg) {
  const int d = blockIdx.x, sec = blockIdx.y, tid = threadIdx.x;
  f16* out = wsf + (size_t)d * PD;
  if (sec == 0) {
    const float* W1d = W1 + d * Hh * 65;
    // W1 hi: swzK64 image, [128][64]
    for (int fid = tid; fid < 1024; fid += 256) {
      int r = fid >> 3, chunk = fid & 7;
      int c0 = (chunk ^ (r & 7)) << 3;
      f16x8 hv;
#pragma unroll
      for (int j = 0; j < 8; j++) hv[j] = (f16)W1d[r * 65 + c0 + j];
      *(f16x8*)&out[fid * 8] = hv;
    }
    // W1 lo: fragment-linear, fid = (t*2+kc)*64 + lane
    for (int fid = tid; fid < 1024; fid += 256) {
      int lane = fid & 63, kc = (fid >> 6) & 1, t = fid >> 7;
      int h = t * 16 + (lane & 15), k = kc * 32 + (lane >> 4) * 8;
      f16x8 lv;
#pragma unroll
      for (int j = 0; j < 8; j++) {
        float v = W1d[h * 65 + k + j];
        f16 hi = (f16)v;
        lv[j] = (f16)((v - (float)hi) * 2048.0f);
      }
      *(f16x8*)&out[8192 + fid * 8] = lv;
    }
    if (tid < 128) w1lg[d * Hh + tid] = W1d[tid * 65 + 64];
  } else {
    const float* g = (sec == 1 ? W2 : W3) + d * Hh * Hh;
    f16* oh = out + (sec == 1 ? 16384 : 49152);
    f16* ol = out + (sec == 1 ? 32768 : 65536);
    // hi: swz image [128][128]
    for (int fid = tid; fid < 2048; fid += 256) {
      int r = fid >> 4, chunk = fid & 15;
      int c0 = (chunk ^ (r & 15)) << 3;
      const float* s = &g[r * 128 + c0];
      float4 v0 = *(const float4*)s, v1 = *(const float4*)(s + 4);
      f16x8 hv = {(f16)v0.x, (f16)v0.y, (f16)v0.z, (f16)v0.w,
                  (f16)v1.x, (f16)v1.y, (f16)v1.z, (f16)v1.w};
      *(f16x8*)&oh[fid * 8] = hv;
    }
    // lo: fragment-linear, fid = (t*4+kc)*64 + lane
    for (int fid = tid; fid < 2048; fid += 256) {
      int lane = fid & 63, kc = (fid >> 6) & 3, t = fid >> 8;
      int h = t * 16 + (lane & 15), k = kc * 32 + (lane >> 4) * 8;
      const float* s = &g[h * 128 + k];
      float4 v0 = *(const float4*)s, v1 = *(const float4*)(s + 4);
      float vv[8] = {v0.x, v0.y, v0.z, v0.w, v1.x, v1.y, v1.z, v1.w};
      f16x8 lv;
#pragma unroll
      for (int j = 0; j < 8; j++) {
        f16 hi = (f16)vv[j];
        lv[j] = (f16)((vv[j] - (float)hi) * 2048.0f);
      }
      *(f16x8*)&ol[fid * 8] = lv;
    }
  }
}

// Mid layer: hi from LDS (full 128 rows), lo streamed from global (frag-linear).
// Each wave: n-tile nt, 4 h-tiles t = wq*4+c2. 24 MFMAs per 8 LDS reads.
__device__ __forceinline__ void mid_phase(
    const f16* AH, const f16* AL, const f16* DH, const f16* DL,
    const f16* WHI, const f16* __restrict__ wlo, int nt, int wq, int l15,
    int quad, int lane, f32x4 (&aP)[4], f32x4 (&aS)[4], f32x4 (&dP)[4],
    f32x4 (&dS)[4]) {
  const int ra = nt * 16 + l15;
  f16x8 loc[4], lon[4];
#pragma unroll
  for (int c2 = 0; c2 < 4; c2++)
    loc[c2] = *(const f16x8*)&wlo[(((wq * 4 + c2) * 4 + 0) * 64 + lane) * 8];
#pragma unroll
  for (int kc = 0; kc < 4; kc++) {
    if (kc < 3) {
#pragma unroll
      for (int c2 = 0; c2 < 4; c2++)
        lon[c2] = *(const f16x8*)&wlo[(((wq * 4 + c2) * 4 + kc + 1) * 64 + lane) * 8];
    }
    int ko = kc * 32 + quad * 8;
    f16x8 xh = *(const f16x8*)&AH[swz(ra, ko)];
    f16x8 xl = *(const f16x8*)&AL[swz(ra, ko)];
    f16x8 yh = *(const f16x8*)&DH[swz(ra, ko)];
    f16x8 yl = *(const f16x8*)&DL[swz(ra, ko)];
#pragma unroll
    for (int c2 = 0; c2 < 4; c2++) {
      int h = (wq * 4 + c2) * 16 + l15;
      f16x8 wh = *(const f16x8*)&WHI[swz(h, ko)];
      aP[c2] = MFMA(wh, xh, aP[c2]);
      aS[c2] = MFMA(loc[c2], xh, aS[c2]);
      aS[c2] = MFMA(wh, xl, aS[c2]);
      dP[c2] = MFMA(wh, yh, dP[c2]);
      dS[c2] = MFMA(loc[c2], yh, dS[c2]);
      dS[c2] = MFMA(wh, yl, dS[c2]);
    }
#pragma unroll
    for (int c2 = 0; c2 < 4; c2++) loc[c2] = lon[c2];
  }
}

__global__ __launch_bounds__(256, 2)
void np_prior_fast(const float* __restrict__ x, const f16* __restrict__ wsw,
                   const float* __restrict__ w1lg,
                   const float* __restrict__ b1, const float* __restrict__ b2,
                   const float* __restrict__ b3, const float* __restrict__ W4,
                   const float* __restrict__ b4,
                   float* __restrict__ out_res, float* __restrict__ out_log) {
  __shared__ float4 smem[4096];  // 64 KB
  f16* AH = (f16*)smem;                     // [32][128] 8 KB
  f16* AL = AH + NT * 128;
  f16* DH = AL + NT * 128;
  f16* DL = DH + NT * 128;
  f16* WHI = (f16*)((char*)smem + 32768);   // 32 KB: full W hi image
  float* A3F = (float*)smem;                // f32 overlay (swzF)
  float* D3F = (float*)((char*)smem + 16384);

  const int tid = threadIdx.x, d = blockIdx.y, n0 = blockIdx.x * NT;
  const int lane = tid & 63, wv = tid >> 6, l15 = lane & 15, quad = lane >> 4;
  const int nt = wv & 1, wq = wv >> 1;  // nt in {0,1}, wq in {0,1}

  const f16* wd = wsw + (size_t)d * PD;
  const float* w1l = w1lg + d * Hh;
  const float* b1d = b1 + d * Hh;
  const f32x4 zero = {0.f, 0.f, 0.f, 0.f};

  // phase 1: W1-hi (16 KB) in flight while splitting x
  cp_lds_async(wd, WHI, 16384, tid);
  for (int i = tid; i < NT * 16; i += 256) {
    int n = i >> 4, k4 = (i & 15) << 2;
    int ng = n0 + n, bb = ng >> 8, tt = ng & 255;
    float4 v = *(const float4*)&x[(bb * 257 + tt) * 64 + k4];
    HL a = split(v.x), b = split(v.y), c = split(v.z), e = split(v.w);
    int o = swz(n, k4);
    *(f16x4*)&AH[o] = f16x4{a.h, b.h, c.h, e.h};
    *(f16x4*)&AL[o] = f16x4{a.l, b.l, c.l, e.l};
  }
  float xtv;
  {
    int ng = n0 + nt * 16 + l15, bb = ng >> 8, tt = ng & 255;
    xtv = x[(bb * 257 + tt + 1) * 64 + d];
  }
  __syncthreads();

  // ---- Layer 1 (K=64): hi in LDS, lo streamed
  f32x4 aP[4], aS[4], dP[4], dS[4];
  {
    const f16* wlo = wd + 8192;
    const int ra = nt * 16 + l15;
    f16x8 lo1[4][2];
#pragma unroll
    for (int c2 = 0; c2 < 4; c2++)
#pragma unroll
      for (int kc = 0; kc < 2; kc++)
        lo1[c2][kc] = *(const f16x8*)&wlo[(((wq * 4 + c2) * 2 + kc) * 64 + lane) * 8];
#pragma unroll
    for (int c2 = 0; c2 < 4; c2++) { aP[c2] = zero; aS[c2] = zero; }
#pragma unroll
    for (int kc = 0; kc < 2; kc++) {
      int ko = kc * 32 + quad * 8;
      f16x8 xh = *(const f16x8*)&AH[swz(ra, ko)];
      f16x8 xl = *(const f16x8*)&AL[swz(ra, ko)];
#pragma unroll
      for (int c2 = 0; c2 < 4; c2++) {
        int h = (wq * 4 + c2) * 16 + l15;
        f16x8 wh = *(const f16x8*)&WHI[swzK64(h, ko)];
        aP[c2] = MFMA(wh, xh, aP[c2]);
        aS[c2] = MFMA(lo1[c2][kc], xh, aS[c2]);
        aS[c2] = MFMA(wh, xl, aS[c2]);
      }
    }
  }
  __syncthreads();
  cp_lds_async(wd + 16384, WHI, 32768, tid);  // W2-hi, overlaps epilogue

  // ---- L1 epilogue: a1 = leaky(p1), d1 = s1 * W1[:,64]
  {
    int n = nt * 16 + l15;
#pragma unroll
    for (int c2 = 0; c2 < 4; c2++) {
      int hb = (wq * 4 + c2) * 16 + quad * 4;
      float4 wv4 = *(const float4*)&w1l[hb];
      float4 bv4 = *(const float4*)&b1d[hb];
      f16x4 ah, al, dh, dl;
#pragma unroll
      for (int j = 0; j < 4; j++) {
        float w1j = (&wv4.x)[j];
        float p = aP[c2][j] + aS[c2][j] * INV2K + xtv * w1j + (&bv4.x)[j];
        float s = p > 0.f ? 1.f : SLP;
        HL av = split(p * s), dv = split(s * w1j);
        ah[j] = av.h; al[j] = av.l; dh[j] = dv.h; dl[j] = dv.l;
      }
      int o = swz(n, hb);
      *(f16x4*)&AH[o] = ah; *(f16x4*)&AL[o] = al;
      *(f16x4*)&DH[o] = dh; *(f16x4*)&DL[o] = dl;
    }
  }
  __syncthreads();

  // ---- Layer 2
#pragma unroll
  for (int c2 = 0; c2 < 4; c2++) { aP[c2] = zero; aS[c2] = zero; dP[c2] = zero; dS[c2] = zero; }
  mid_phase(AH, AL, DH, DL, WHI, wd + 32768, nt, wq, l15, quad, lane, aP, aS, dP, dS);
  __syncthreads();
  cp_lds_async(wd + 49152, WHI, 32768, tid);  // W3-hi

  // ---- L2 epilogue
  {
    const float* b2d = b2 + d * Hh;
    int n = nt * 16 + l15;
#pragma unroll
    for (int c2 = 0; c2 < 4; c2++) {
      int hb = (wq * 4 + c2) * 16 + quad * 4;
      float4 bv4 = *(const float4*)&b2d[hb];
      f16x4 ah, al, dh, dl;
#pragma unroll
      for (int j = 0; j < 4; j++) {
        float p = aP[c2][j] + aS[c2][j] * INV2K + (&bv4.x)[j];
        float s = p > 0.f ? 1.f : SLP;
        float dd = s * (dP[c2][j] + dS[c2][j] * INV2K);
        HL av = split(p * s), dv = split(dd);
        ah[j] = av.h; al[j] = av.l; dh[j] = dv.h; dl[j] = dv.l;
      }
      int o = swz(n, hb);
      *(f16x4*)&AH[o] = ah; *(f16x4*)&AL[o] = al;
      *(f16x4*)&DH[o] = dh; *(f16x4*)&DL[o] = dl;
    }
  }
  __syncthreads();

  // ---- Layer 3
#pragma unroll
  for (int c2 = 0; c2 < 4; c2++) { aP[c2] = zero; aS[c2] = zero; dP[c2] = zero; dS[c2] = zero; }
  mid_phase(AH, AL, DH, DL, WHI, wd + 65536, nt, wq, l15, quad, lane, aP, aS, dP, dS);
  __syncthreads();  // act reads done; f32 overlay safe

  // ---- L3 epilogue -> swizzled f32 overlay
  {
    const float* b3d = b3 + d * Hh;
    int n = nt * 16 + l15;
#pragma unroll
    for (int c2 = 0; c2 < 4; c2++) {
      int hb = (wq * 4 + c2) * 16 + quad * 4;
      float4 bv4 = *(const float4*)&b3d[hb];
      float4 pa, pd;
#pragma unroll
      for (int j = 0; j < 4; j++) {
        float p = aP[c2][j] + aS[c2][j] * INV2K + (&bv4.x)[j];
        float s = p > 0.f ? 1.f : SLP;
        (&pa.x)[j] = p * s;
        (&pd.x)[j] = s * (dP[c2][j] + dS[c2][j] * INV2K);
      }
      *(float4*)&A3F[swzF(n, hb)] = pa;
      *(float4*)&D3F[swzF(n, hb)] = pd;
    }
  }
  __syncthreads();

  // ---- Layer 4: fp32 VALU dot, 8 threads per sample
  {
    int n = tid >> 3, oct = tid & 7;
    const float* w4d = W4 + d * Hh;
    float sr = 0.f, sd = 0.f;
#pragma unroll
    for (int i = 0; i < 4; i++) {
      int c = oct * 16 + i * 4;
      float4 va = *(const float4*)&A3F[swzF(n, c)];
      float4 vd = *(const float4*)&D3F[swzF(n, c)];
      float4 w = *(const float4*)&w4d[c];
      sr += va.x * w.x + va.y * w.y + va.z * w.z + va.w * w.w;
      sd += vd.x * w.x + vd.y * w.y + vd.z * w.z + vd.w * w.w;
    }
    sr += __shfl_xor(sr, 1); sr += __shfl_xor(sr, 2); sr += __shfl_xor(sr, 4);
    sd += __shfl_xor(sd, 1); sd += __shfl_xor(sd, 2); sd += __shfl_xor(sd, 4);
    if (oct == 0) {
      int ng = n0 + n;
      out_res[ng * 64 + d] = sr + b4[d];
      atomicAdd(&out_log[ng], logf(fabsf(sd) + 1e-8f));
    }
  }
}

// ---------------- fallback (no-ws path) --------------------------------------
__device__ __forceinline__ void stage_wf(f16* WH, f16* WL,
                                         const float* __restrict__ g, int tid) {
  for (int i = tid; i < 2048; i += 256) {
    int h = i >> 5, k4 = (i & 31) << 2;
    float4 v = ((const float4*)g)[i];
    HL a = split(v.x), b = split(v.y), c = split(v.z), e = split(v.w);
    int o = swz(h, k4);
    *(f16x4*)&WH[o] = f16x4{a.h, b.h, c.h, e.h};
    *(f16x4*)&WL[o] = f16x4{a.l, b.l, c.l, e.l};
  }
}

__device__ __forceinline__ void mid_mfma_half(
    const f16* AH, const f16* AL, const f16* DH, const f16* DL,
    const f16* WH, const f16* WL, int nt, int wq, int l15, int quad,
    f32x4* aP, f32x4* aS, f32x4* dP, f32x4* dS) {
#pragma unroll
  for (int kc = 0; kc < 4; kc++) {
    int ko = kc * 32 + quad * 8;
    int ra = nt * 16 + l15;
    f16x8 xh = *(const f16x8*)&AH[swz(ra, ko)];
    f16x8 xl = *(const f16x8*)&AL[swz(ra, ko)];
    f16x8 yh = *(const f16x8*)&DH[swz(ra, ko)];
    f16x8 yl = *(const f16x8*)&DL[swz(ra, ko)];
#pragma unroll
    for (int c2 = 0; c2 < 2; c2++) {
      int hr = (2 * wq + c2) * 16 + l15;
      f16x8 wh = *(const f16x8*)&WH[swz(hr, ko)];
      f16x8 wl = *(const f16x8*)&WL[swz(hr, ko)];
      aP[c2] = MFMA(wh, xh, aP[c2]);
      aS[c2] = MFMA(wl, xh, aS[c2]);
      aS[c2] = MFMA(wh, xl, aS[c2]);
      dP[c2] = MFMA(wh, yh, dP[c2]);
      dS[c2] = MFMA(wl, yh, dS[c2]);
      dS[c2] = MFMA(wh, yl, dS[c2]);
    }
  }
}

__global__ __launch_bounds__(256, 2)
void np_prior_fb(const float* __restrict__ x,
                 const float* __restrict__ W1, const float* __restrict__ b1,
                 const float* __restrict__ W2, const float* __restrict__ b2,
                 const float* __restrict__ W3, const float* __restrict__ b3,
                 const float* __restrict__ W4, const float* __restrict__ b4,
                 float* __restrict__ out_res, float* __restrict__ out_log) {
  __shared__ float4 smem[4096];
  f16* AH = (f16*)smem;
  f16* AL = AH + NT * 128;
  f16* DH = AL + NT * 128;
  f16* DL = DH + NT * 128;
  f16* WHp = (f16*)((char*)smem + 32768);
  f16* WLp = WHp + 64 * 128;
  float* A3F = (float*)smem;
  float* D3F = (float*)((char*)smem + 16384);

  const int tid = threadIdx.x, d = blockIdx.y, n0 = blockIdx.x * NT;
  const int lane = tid & 63, wv = tid >> 6, l15 = lane & 15, quad = lane >> 4;
  const int nt = wv & 1, wq = wv >> 1;

  const float* W1d = W1 + d * Hh * 65;
  const float* b1d = b1 + d * Hh;
  const f32x4 zero = {0.f, 0.f, 0.f, 0.f};

  for (int i = tid; i < NT * 16; i += 256) {
    int n = i >> 4, k4 = (i & 15) << 2;
    int ng = n0 + n, bb = ng >> 8, tt = ng & 255;
    float4 v = *(const float4*)&x[(bb * 257 + tt) * 64 + k4];
    HL a = split(v.x), b = split(v.y), c = split(v.z), e = split(v.w);
    int o = swz(n, k4);
    *(f16x4*)&AH[o] = f16x4{a.h, b.h, c.h, e.h};
    *(f16x4*)&AL[o] = f16x4{a.l, b.l, c.l, e.l};
  }
  float xtv;
  {
    int ng = n0 + nt * 16 + l15, bb = ng >> 8, tt = ng & 255;
    xtv = x[(bb * 257 + tt + 1) * 64 + d];
  }
  for (int i = tid; i < 64 * 64; i += 256) {
    int h = i >> 6, k = i & 63;
    HL s = split(W1d[h * 65 + k]);
    int o = swz(h, k);
    WHp[o] = s.h; WLp[o] = s.l;
  }
  __syncthreads();

  f32x4 l1P[2][2], l1S[2][2];
  for (int hf = 0; hf < 2; hf++) {
    if (hf == 1) {
      __syncthreads();
      for (int i = tid; i < 64 * 64; i += 256) {
        int h = i >> 6, k = i & 63;
        HL s = split(W1d[(64 + h) * 65 + k]);
        int o = swz(h, k);
        WHp[o] = s.h; WLp[o] = s.l;
      }
      __syncthreads();
    }
    l1P[hf][0] = zero; l1P[hf][1] = zero;
    l1S[hf][0] = zero; l1S[hf][1] = zero;
#pragma unroll
    for (int kc = 0; kc < 2; kc++) {
      int ko = kc * 32 + quad * 8;
      f16x8 xh = *(const f16x8*)&AH[swz(nt * 16 + l15, ko)];
      f16x8 xl = *(const f16x8*)&AL[swz(nt * 16 + l15, ko)];
#pragma unroll
      for (int c2 = 0; c2 < 2; c2++) {
        int hr = (2 * wq + c2) * 16 + l15;
        f16x8 wh = *(const f16x8*)&WHp[swz(hr, ko)];
        f16x8 wl = *(const f16x8*)&WLp[swz(hr, ko)];
        l1P[hf][c2] = MFMA(wh, xh, l1P[hf][c2]);
        l1S[hf][c2] = MFMA(wl, xh, l1S[hf][c2]);
        l1S[hf][c2] = MFMA(wh, xl, l1S[hf][c2]);
      }
    }
  }
  __syncthreads();

  {
    int n = nt * 16 + l15;
#pragma unroll
    for (int hf = 0; hf < 2; hf++)
#pragma unroll
      for (int c2 = 0; c2 < 2; c2++) {
        int hb = hf * 64 + (2 * wq + c2) * 16 + quad * 4;
        f16x4 ah, al, dh, dl;
#pragma unroll
        for (int j = 0; j < 4; j++) {
          int h = hb + j;
          float w1j = W1d[h * 65 + 64];
          float p = l1P[hf][c2][j] + l1S[hf][c2][j] * INV2K + xtv * w1j + b1d[h];
          float s = p > 0.f ? 1.f : SLP;
          HL av = split(p * s), dv = split(s * w1j);
          ah[j] = av.h; al[j] = av.l; dh[j] = dv.h; dl[j] = dv.l;
        }
        int o = swz(n, hb);
        *(f16x4*)&AH[o] = ah; *(f16x4*)&AL[o] = al;
        *(f16x4*)&DH[o] = dh; *(f16x4*)&DL[o] = dl;
      }
  }
  stage_wf(WHp, WLp, W2 + d * Hh * Hh, tid);
  __syncthreads();

  f32x4 aP[2][2], aS[2][2], dP[2][2], dS[2][2];
  for (int hf = 0; hf < 2; hf++) {
    if (hf == 1) {
      __syncthreads();
      stage_wf(WHp, WLp, W2 + d * Hh * Hh + 64 * 128, tid);
      __syncthreads();
    }
    aP[hf][0] = zero; aP[hf][1] = zero; aS[hf][0] = zero; aS[hf][1] = zero;
    dP[hf][0] = zero; dP[hf][1] = zero; dS[hf][0] = zero; dS[hf][1] = zero;
    mid_mfma_half(AH, AL, DH, DL, WHp, WLp, nt, wq, l15, quad,
                  aP[hf], aS[hf], dP[hf], dS[hf]);
  }
  __syncthreads();

  {
    const float* b2d = b2 + d * Hh;
    int n = nt * 16 + l15;
#pragma unroll
    for (int hf = 0; hf < 2; hf++)
#pragma unroll
      for (int c2 = 0; c2 < 2; c2++) {
        int hb = hf * 64 + (2 * wq + c2) * 16 + quad * 4;
        f16x4 ah, al, dh, dl;
#pragma unroll
        for (int j = 0; j < 4; j++) {
          int h = hb + j;
          float p = aP[hf][c2][j] + aS[hf][c2][j] * INV2K + b2d[h];
          float s = p > 0.f ? 1.f : SLP;
          float dd = s * (dP[hf][c2][j] + dS[hf][c2][j] * INV2K);
          HL av = split(p * s), dv = split(dd);
          ah[j] = av.h; al[j] = av.l; dh[j] = dv.h; dl[j] = dv.l;
        }
        int o = swz(n, hb);
        *(f16x4*)&AH[o] = ah; *(f16x4*)&AL[o] = al;
        *(f16x4*)&DH[o] = dh; *(f16x4*)&DL[o] = dl;
      }
  }
  stage_wf(WHp, WLp, W3 + d * Hh * Hh, tid);
  __syncthreads();

  for (int hf = 0; hf < 2; hf++) {
    if (hf == 1) {
      __syncthreads();
      stage_wf(WHp, WLp, W3 + d * Hh * Hh + 64 * 128, tid);
      __syncthreads();
    }
    aP[hf][0] = zero; aP[hf][1] = zero; aS[hf][0] = zero; aS[hf][1] = zero;
    dP[hf][0] = zero; dP[hf][1] = zero; dS[hf][0] = zero; dS[hf][1] = zero;
    mid_mfma_half(AH, AL, DH, DL, WHp, WLp, nt, wq, l15, quad,
                  aP[hf], aS[hf], dP[hf], dS[hf]);
  }
  __syncthreads();

  {
    const float* b3d = b3 + d * Hh;
    int n = nt * 16 + l15;
#pragma unroll
    for (int hf = 0; hf < 2; hf++)
#pragma unroll
      for (int c2 = 0; c2 < 2; c2++) {
        int hb = hf * 64 + (2 * wq + c2) * 16 + quad * 4;
        float4 pa, pd;
#pragma unroll
        for (int j = 0; j < 4; j++) {
          int h = hb + j;
          float p = aP[hf][c2][j] + aS[hf][c2][j] * INV2K + b3d[h];
          float s = p > 0.f ? 1.f : SLP;
          (&pa.x)[j] = p * s;
          (&pd.x)[j] = s * (dP[hf][c2][j] + dS[hf][c2][j] * INV2K);
        }
        *(float4*)&A3F[swzF(n, hb)] = pa;
        *(float4*)&D3F[swzF(n, hb)] = pd;
      }
  }
  __syncthreads();

  {
    int n = tid >> 3, oct = tid & 7;
    const float* w4d = W4 + d * Hh;
    float sr = 0.f, sd = 0.f;
#pragma unroll
    for (int i = 0; i < 4; i++) {
      int c = oct * 16 + i * 4;
      float4 va = *(const float4*)&A3F[swzF(n, c)];
      float4 vd = *(const float4*)&D3F[swzF(n, c)];
      float4 w = *(const float4*)&w4d[c];
      sr += va.x * w.x + va.y * w.y + va.z * w.z + va.w * w.w;
      sd += vd.x * w.x + vd.y * w.y + vd.z * w.z + vd.w * w.w;
    }
    sr += __shfl_xor(sr, 1); sr += __shfl_xor(sr, 2); sr += __shfl_xor(sr, 4);
    sd += __shfl_xor(sd, 1); sd += __shfl_xor(sd, 2); sd += __shfl_xor(sd, 4);
    if (oct == 0) {
      int ng = n0 + n;
      out_res[ng * 64 + d] = sr + b4[d];
      atomicAdd(&out_log[ng], logf(fabsf(sd) + 1e-8f));
    }
  }
}

extern "C" void kernel_launch(void* const* d_in, const int* in_sizes, int n_in,
                              void* d_out, int out_size, void* d_ws, size_t ws_size,
                              hipStream_t stream) {
  (void)in_sizes; (void)n_in; (void)out_size;
  const float* x  = (const float*)d_in[0];
  const float* W1 = (const float*)d_in[1];
  const float* b1 = (const float*)d_in[2];
  const float* W2 = (const float*)d_in[3];
  const float* b2 = (const float*)d_in[4];
  const float* W3 = (const float*)d_in[5];
  const float* b3 = (const float*)d_in[6];
  const float* W4 = (const float*)d_in[7];
  const float* b4 = (const float*)d_in[8];

  float* out_res = (float*)d_out;
  float* out_log = out_res + Nn * Dd;
  hipMemsetAsync(out_log, 0, Nn * sizeof(float), stream);

  dim3 grid(Nn / NT, Dd);
  if (ws_size >= WS_NEEDED) {
    f16* wsf = (f16*)d_ws;
    float* w1lg = (float*)((char*)d_ws + W1L_OFF);
    prep_kernel<<<dim3(Dd, 3), 256, 0, stream>>>(W1, W2, W3, wsf, w1lg);
    np_prior_fast<<<grid, 256, 0, stream>>>(x, wsf, w1lg, b1, b2, b3, W4, b4,
                                            out_res, out_log);
  } else {
    np_prior_fb<<<grid, 256, 0, stream>>>(x, W1, b1, W2, b2, W3, b3, W4, b4,
                                          out_res, out_log);
  }
}

// Round 5
// 248.025 us; speedup vs baseline: 1.1560x; 1.1560x over previous
//
#include <hip/hip_runtime.h>
#include <hip/hip_bf16.h>
#include <math.h>

typedef _Float16 f16;
typedef _Float16 f16x8 __attribute__((ext_vector_type(8)));
typedef _Float16 f16x4 __attribute__((ext_vector_type(4)));
typedef _Float16 f16x2 __attribute__((ext_vector_type(2)));
typedef float f32x4 __attribute__((ext_vector_type(4)));

#define MFMA(a, b, c) __builtin_amdgcn_mfma_f32_16x16x32_f16((a), (b), (c), 0, 0, 0)

constexpr int Dd = 64;
constexpr int Hh = 128;
constexpr int Nn = 4096;
constexpr int NT = 32;
constexpr float SLP = 0.2f;
constexpr float INV2K = 1.0f / 2048.0f;

// Per-d f16 layout in d_ws (preprocessed, pre-swizzled, hi/lo split):
//   [0,8192)      W1 half0: hi 4096 | lo 4096   (compact K=64 swizzle)
//   [8192,16384)  W1 half1
//   [16384,49152) W2: h0 (hi 8192 | lo 8192), h1
//   [49152,81920) W3: h0, h1
constexpr int PD = 81920;
constexpr size_t W1L_OFF = (size_t)Dd * PD * 2;  // bytes; then w1last f32[64][128]
constexpr size_t WS_NEEDED = W1L_OFF + (size_t)Dd * Hh * 4;

// XOR swizzle, [r][128] f16, 8-elem chunks, chunk ^= r&15 (2-way max = free)
__device__ __forceinline__ int swz(int r, int c) {
  return (r << 7) + ((((c >> 3) ^ (r & 15)) << 3) | (c & 7));
}
// Compact K=64 swizzle, [r][64] f16, chunk ^= r&7
__device__ __forceinline__ int swzK64(int r, int c) {
  return (r << 6) + (((((c >> 3) ^ r) & 7) << 3) | (c & 7));
}
// f32 overlay swizzle, [n][128] f32, 4-elem chunks
__device__ __forceinline__ int swzF(int n, int h) {
  return (n << 7) + ((((h >> 2) ^ n) & 31) << 2) + (h & 3);
}

struct HL { f16 h, l; };
__device__ __forceinline__ HL split(float v) {
  HL r;
  r.h = (f16)v;
  r.l = (f16)((v - (float)r.h) * 2048.0f);
  return r;
}

// Async contiguous global->LDS, 512 threads: nbytes multiple of 8192
__device__ __forceinline__ void cp_lds_async512(const void* g, void* l, int nbytes, int tid) {
  const int lane = tid & 63, wv = tid >> 6;
  for (int base = wv * 1024; base < nbytes; base += 8192) {
    __builtin_amdgcn_global_load_lds(
        (const __attribute__((address_space(1))) void*)((const char*)g + base + lane * 16),
        (__attribute__((address_space(3))) void*)((char*)l + base), 16, 0, 0);
  }
}

// ---------------- preprocess: split + pre-swizzle weights into d_ws ----------
// Also zeroes out_log (sec 0) so no separate memset dispatch is needed.
__global__ __launch_bounds__(256)
void prep_kernel(const float* __restrict__ W1, const float* __restrict__ W2,
                 const float* __restrict__ W3, f16* __restrict__ wsf,
                 float* __restrict__ w1lg, float* __restrict__ out_log) {
  const int d = blockIdx.x, sec = blockIdx.y, tid = threadIdx.x;
  f16* out = wsf + (size_t)d * PD;
  if (sec == 0) {
    const float* W1d = W1 + d * Hh * 65;
    for (int ip = tid; ip < 4096; ip += 256) {  // pairs over 128x64
      int h = ip >> 5, k2 = (ip & 31) << 1;
      HL a = split(W1d[h * 65 + k2]);
      HL b = split(W1d[h * 65 + k2 + 1]);
      int o = (h >> 6) * 8192 + swzK64(h & 63, k2);
      *(f16x2*)&out[o] = f16x2{a.h, b.h};
      *(f16x2*)&out[o + 4096] = f16x2{a.l, b.l};
    }
    if (tid < 128) w1lg[d * Hh + tid] = W1d[tid * 65 + 64];
    if (tid < 64) out_log[d * 64 + tid] = 0.f;  // 64 blocks x 64 = 4096
  } else {
    int w = (sec - 1) >> 1, hh = (sec - 1) & 1;  // w: 0=W2 1=W3
    const float* g = (w == 0 ? W2 : W3) + d * Hh * Hh + hh * 8192;
    f16* ob = out + 16384 + w * 32768 + hh * 16384;
    for (int ip = tid; ip < 4096; ip += 256) {  // pairs over 64x128
      int h = ip >> 6, k2 = (ip & 63) << 1;
      float2 v = *(const float2*)&g[h * 128 + k2];
      HL a = split(v.x), b = split(v.y);
      int o = swz(h, k2);
      *(f16x2*)&ob[o] = f16x2{a.h, b.h};
      *(f16x2*)&ob[o + 8192] = f16x2{a.l, b.l};
    }
  }
}

// One W-half of a mid layer, one h-tile per wave. All operands from LDS.
__device__ __forceinline__ void mid_half(
    const f16* AH, const f16* AL, const f16* DH, const f16* DL,
    const f16* WH, const f16* WL, int ra, int hr, int quad,
    f32x4& aP, f32x4& aS, f32x4& dP, f32x4& dS) {
#pragma unroll
  for (int kc = 0; kc < 4; kc++) {
    int ko = kc * 32 + quad * 8;
    f16x8 xh = *(const f16x8*)&AH[swz(ra, ko)];
    f16x8 xl = *(const f16x8*)&AL[swz(ra, ko)];
    f16x8 yh = *(const f16x8*)&DH[swz(ra, ko)];
    f16x8 yl = *(const f16x8*)&DL[swz(ra, ko)];
    f16x8 wh = *(const f16x8*)&WH[swz(hr, ko)];
    f16x8 wl = *(const f16x8*)&WL[swz(hr, ko)];
    aP = MFMA(wh, xh, aP);
    aS = MFMA(wl, xh, aS);
    aS = MFMA(wh, xl, aS);
    dP = MFMA(wh, yh, dP);
    dS = MFMA(wl, yh, dS);
    dS = MFMA(wh, yl, dS);
  }
}

// 512 threads (8 waves): nt = wv&1 picks the 16-sample tile, wq = wv>>1 picks
// the h-tile within the staged 64-row W half. 64 KB LDS -> 2 blocks/CU ->
// 16 waves/CU (4/SIMD) for latency hiding.
__global__ __launch_bounds__(512, 4)
void np_prior_fast(const float* __restrict__ x, const f16* __restrict__ wsw,
                   const float* __restrict__ w1lg,
                   const float* __restrict__ b1, const float* __restrict__ b2,
                   const float* __restrict__ b3, const float* __restrict__ W4,
                   const float* __restrict__ b4,
                   float* __restrict__ out_res, float* __restrict__ out_log) {
  __shared__ float4 smem[4096];  // 64 KB
  f16* AH = (f16*)smem;                     // [32][128] 8 KB each plane
  f16* AL = AH + NT * 128;
  f16* DH = AL + NT * 128;
  f16* DL = DH + NT * 128;
  f16* Wreg = (f16*)((char*)smem + 32768);  // 32 KB W staging (hi | lo)
  float* A3F = (float*)smem;                // f32 overlay (swzF), 16 KB
  float* D3F = (float*)((char*)smem + 16384);

  const int tid = threadIdx.x, d = blockIdx.y, n0 = blockIdx.x * NT;
  const int lane = tid & 63, wv = tid >> 6, l15 = lane & 15, quad = lane >> 4;
  const int nt = wv & 1, wq = wv >> 1;  // nt 0..1, wq 0..3
  const int ra = nt * 16 + l15;         // act row (n within block)
  const int hr = wq * 16 + l15;         // W row within the staged half

  const f16* wd = wsw + (size_t)d * PD;
  const float* w1l = w1lg + d * Hh;
  const float* b1d = b1 + d * Hh;
  const f32x4 zero = {0.f, 0.f, 0.f, 0.f};

  // W1-h0 in flight while splitting x (one element group per thread)
  cp_lds_async512(wd, Wreg, 16384, tid);
  {
    int n = tid >> 4, k4 = (tid & 15) << 2;
    int ng = n0 + n, bb = ng >> 8, tt = ng & 255;
    float4 v = *(const float4*)&x[(bb * 257 + tt) * 64 + k4];
    HL a = split(v.x), b = split(v.y), c = split(v.z), e = split(v.w);
    int o = swz(n, k4);
    *(f16x4*)&AH[o] = f16x4{a.h, b.h, c.h, e.h};
    *(f16x4*)&AL[o] = f16x4{a.l, b.l, c.l, e.l};
  }
  float xtv;
  {
    int ng = n0 + ra, bb = ng >> 8, tt = ng & 255;
    xtv = x[(bb * 257 + tt + 1) * 64 + d];
  }
  __syncthreads();

  // ---- Layer 1 (K=64): one h-tile per wave per half
  f32x4 l1P[2], l1S[2];
#pragma unroll
  for (int hf = 0; hf < 2; hf++) {
    if (hf == 1) {
      __syncthreads();
      cp_lds_async512(wd + 8192, Wreg, 16384, tid);
      __syncthreads();
    }
    l1P[hf] = zero; l1S[hf] = zero;
#pragma unroll
    for (int kc = 0; kc < 2; kc++) {
      int ko = kc * 32 + quad * 8;
      f16x8 xh = *(const f16x8*)&AH[swz(ra, ko)];
      f16x8 xl = *(const f16x8*)&AL[swz(ra, ko)];
      f16x8 wh = *(const f16x8*)&Wreg[swzK64(hr, ko)];
      f16x8 wl = *(const f16x8*)&Wreg[4096 + swzK64(hr, ko)];
      l1P[hf] = MFMA(wh, xh, l1P[hf]);
      l1S[hf] = MFMA(wl, xh, l1S[hf]);
      l1S[hf] = MFMA(wh, xl, l1S[hf]);
    }
  }
  __syncthreads();
  cp_lds_async512(wd + 16384, Wreg, 32768, tid);  // W2-h0, overlaps epilogue

  // ---- L1 epilogue: a1 = leaky(p1), d1 = s1 * W1[:,64]
#pragma unroll
  for (int hf = 0; hf < 2; hf++) {
    int hb = hf * 64 + wq * 16 + quad * 4;
    float4 wv4 = *(const float4*)&w1l[hb];
    float4 bv4 = *(const float4*)&b1d[hb];
    f16x4 ah, al, dh, dl;
#pragma unroll
    for (int j = 0; j < 4; j++) {
      float w1j = (&wv4.x)[j];
      float p = l1P[hf][j] + l1S[hf][j] * INV2K + xtv * w1j + (&bv4.x)[j];
      float s = p > 0.f ? 1.f : SLP;
      HL av = split(p * s), dv = split(s * w1j);
      ah[j] = av.h; al[j] = av.l; dh[j] = dv.h; dl[j] = dv.l;
    }
    int o = swz(ra, hb);
    *(f16x4*)&AH[o] = ah; *(f16x4*)&AL[o] = al;
    *(f16x4*)&DH[o] = dh; *(f16x4*)&DL[o] = dl;
  }
  __syncthreads();

  // ---- Layer 2
  f32x4 aP[2], aS[2], dP[2], dS[2];
#pragma unroll
  for (int hf = 0; hf < 2; hf++) {
    if (hf == 1) {
      __syncthreads();
      cp_lds_async512(wd + 32768, Wreg, 32768, tid);  // W2-h1
      __syncthreads();
    }
    aP[hf] = zero; aS[hf] = zero; dP[hf] = zero; dS[hf] = zero;
    mid_half(AH, AL, DH, DL, Wreg, Wreg + 8192, ra, hr, quad,
             aP[hf], aS[hf], dP[hf], dS[hf]);
  }
  __syncthreads();
  cp_lds_async512(wd + 49152, Wreg, 32768, tid);  // W3-h0

  // ---- L2 epilogue
  {
    const float* b2d = b2 + d * Hh;
#pragma unroll
    for (int hf = 0; hf < 2; hf++) {
      int hb = hf * 64 + wq * 16 + quad * 4;
      float4 bv4 = *(const float4*)&b2d[hb];
      f16x4 ah, al, dh, dl;
#pragma unroll
      for (int j = 0; j < 4; j++) {
        float p = aP[hf][j] + aS[hf][j] * INV2K + (&bv4.x)[j];
        float s = p > 0.f ? 1.f : SLP;
        float dd = s * (dP[hf][j] + dS[hf][j] * INV2K);
        HL av = split(p * s), dv = split(dd);
        ah[j] = av.h; al[j] = av.l; dh[j] = dv.h; dl[j] = dv.l;
      }
      int o = swz(ra, hb);
      *(f16x4*)&AH[o] = ah; *(f16x4*)&AL[o] = al;
      *(f16x4*)&DH[o] = dh; *(f16x4*)&DL[o] = dl;
    }
  }
  __syncthreads();

  // ---- Layer 3
#pragma unroll
  for (int hf = 0; hf < 2; hf++) {
    if (hf == 1) {
      __syncthreads();
      cp_lds_async512(wd + 65536, Wreg, 32768, tid);  // W3-h1
      __syncthreads();
    }
    aP[hf] = zero; aS[hf] = zero; dP[hf] = zero; dS[hf] = zero;
    mid_half(AH, AL, DH, DL, Wreg, Wreg + 8192, ra, hr, quad,
             aP[hf], aS[hf], dP[hf], dS[hf]);
  }
  __syncthreads();  // all act reads done; f32 overlay becomes safe

  // ---- L3 epilogue -> swizzled f32 overlay
  {
    const float* b3d = b3 + d * Hh;
#pragma unroll
    for (int hf = 0; hf < 2; hf++) {
      int hb = hf * 64 + wq * 16 + quad * 4;
      float4 bv4 = *(const float4*)&b3d[hb];
      float4 pa, pd;
#pragma unroll
      for (int j = 0; j < 4; j++) {
        float p = aP[hf][j] + aS[hf][j] * INV2K + (&bv4.x)[j];
        float s = p > 0.f ? 1.f : SLP;
        (&pa.x)[j] = p * s;
        (&pd.x)[j] = s * (dP[hf][j] + dS[hf][j] * INV2K);
      }
      *(float4*)&A3F[swzF(ra, hb)] = pa;
      *(float4*)&D3F[swzF(ra, hb)] = pd;
    }
  }
  __syncthreads();

  // ---- Layer 4: fp32 VALU dot, 16 threads per sample
  {
    int n = tid >> 4, g16 = tid & 15;
    const float* w4d = W4 + d * Hh;
    int c = g16 * 8;
    float4 va0 = *(const float4*)&A3F[swzF(n, c)];
    float4 va1 = *(const float4*)&A3F[swzF(n, c + 4)];
    float4 vd0 = *(const float4*)&D3F[swzF(n, c)];
    float4 vd1 = *(const float4*)&D3F[swzF(n, c + 4)];
    float4 w0 = *(const float4*)&w4d[c];
    float4 w1 = *(const float4*)&w4d[c + 4];
    float sr = va0.x * w0.x + va0.y * w0.y + va0.z * w0.z + va0.w * w0.w +
               va1.x * w1.x + va1.y * w1.y + va1.z * w1.z + va1.w * w1.w;
    float sd = vd0.x * w0.x + vd0.y * w0.y + vd0.z * w0.z + vd0.w * w0.w +
               vd1.x * w1.x + vd1.y * w1.y + vd1.z * w1.z + vd1.w * w1.w;
    sr += __shfl_xor(sr, 1); sr += __shfl_xor(sr, 2);
    sr += __shfl_xor(sr, 4); sr += __shfl_xor(sr, 8);
    sd += __shfl_xor(sd, 1); sd += __shfl_xor(sd, 2);
    sd += __shfl_xor(sd, 4); sd += __shfl_xor(sd, 8);
    if (g16 == 0) {
      int ng = n0 + n;
      out_res[ng * 64 + d] = sr + b4[d];
      atomicAdd(&out_log[ng], logf(fabsf(sd) + 1e-8f));
    }
  }
}

// ---------------- fallback (no-ws path, 256 threads) -------------------------
__device__ __forceinline__ void stage_wf(f16* WH, f16* WL,
                                         const float* __restrict__ g, int tid) {
  for (int i = tid; i < 2048; i += 256) {
    int h = i >> 5, k4 = (i & 31) << 2;
    float4 v = ((const float4*)g)[i];
    HL a = split(v.x), b = split(v.y), c = split(v.z), e = split(v.w);
    int o = swz(h, k4);
    *(f16x4*)&WH[o] = f16x4{a.h, b.h, c.h, e.h};
    *(f16x4*)&WL[o] = f16x4{a.l, b.l, c.l, e.l};
  }
}

__device__ __forceinline__ void mid_mfma_half(
    const f16* AH, const f16* AL, const f16* DH, const f16* DL,
    const f16* WH, const f16* WL, int nt, int wq, int l15, int quad,
    f32x4* aP, f32x4* aS, f32x4* dP, f32x4* dS) {
#pragma unroll
  for (int kc = 0; kc < 4; kc++) {
    int ko = kc * 32 + quad * 8;
    int ra = nt * 16 + l15;
    f16x8 xh = *(const f16x8*)&AH[swz(ra, ko)];
    f16x8 xl = *(const f16x8*)&AL[swz(ra, ko)];
    f16x8 yh = *(const f16x8*)&DH[swz(ra, ko)];
    f16x8 yl = *(const f16x8*)&DL[swz(ra, ko)];
#pragma unroll
    for (int c2 = 0; c2 < 2; c2++) {
      int hr = (2 * wq + c2) * 16 + l15;
      f16x8 wh = *(const f16x8*)&WH[swz(hr, ko)];
      f16x8 wl = *(const f16x8*)&WL[swz(hr, ko)];
      aP[c2] = MFMA(wh, xh, aP[c2]);
      aS[c2] = MFMA(wl, xh, aS[c2]);
      aS[c2] = MFMA(wh, xl, aS[c2]);
      dP[c2] = MFMA(wh, yh, dP[c2]);
      dS[c2] = MFMA(wl, yh, dS[c2]);
      dS[c2] = MFMA(wh, yl, dS[c2]);
    }
  }
}

__global__ __launch_bounds__(256, 2)
void np_prior_fb(const float* __restrict__ x,
                 const float* __restrict__ W1, const float* __restrict__ b1,
                 const float* __restrict__ W2, const float* __restrict__ b2,
                 const float* __restrict__ W3, const float* __restrict__ b3,
                 const float* __restrict__ W4, const float* __restrict__ b4,
                 float* __restrict__ out_res, float* __restrict__ out_log) {
  __shared__ float4 smem[4096];
  f16* AH = (f16*)smem;
  f16* AL = AH + NT * 128;
  f16* DH = AL + NT * 128;
  f16* DL = DH + NT * 128;
  f16* WHp = (f16*)((char*)smem + 32768);
  f16* WLp = WHp + 64 * 128;
  float* A3F = (float*)smem;
  float* D3F = (float*)((char*)smem + 16384);

  const int tid = threadIdx.x, d = blockIdx.y, n0 = blockIdx.x * NT;
  const int lane = tid & 63, wv = tid >> 6, l15 = lane & 15, quad = lane >> 4;
  const int nt = wv & 1, wq = wv >> 1;

  const float* W1d = W1 + d * Hh * 65;
  const float* b1d = b1 + d * Hh;
  const f32x4 zero = {0.f, 0.f, 0.f, 0.f};

  for (int i = tid; i < NT * 16; i += 256) {
    int n = i >> 4, k4 = (i & 15) << 2;
    int ng = n0 + n, bb = ng >> 8, tt = ng & 255;
    float4 v = *(const float4*)&x[(bb * 257 + tt) * 64 + k4];
    HL a = split(v.x), b = split(v.y), c = split(v.z), e = split(v.w);
    int o = swz(n, k4);
    *(f16x4*)&AH[o] = f16x4{a.h, b.h, c.h, e.h};
    *(f16x4*)&AL[o] = f16x4{a.l, b.l, c.l, e.l};
  }
  float xtv;
  {
    int ng = n0 + nt * 16 + l15, bb = ng >> 8, tt = ng & 255;
    xtv = x[(bb * 257 + tt + 1) * 64 + d];
  }
  for (int i = tid; i < 64 * 64; i += 256) {
    int h = i >> 6, k = i & 63;
    HL s = split(W1d[h * 65 + k]);
    int o = swz(h, k);
    WHp[o] = s.h; WLp[o] = s.l;
  }
  __syncthreads();

  f32x4 l1P[2][2], l1S[2][2];
  for (int hf = 0; hf < 2; hf++) {
    if (hf == 1) {
      __syncthreads();
      for (int i = tid; i < 64 * 64; i += 256) {
        int h = i >> 6, k = i & 63;
        HL s = split(W1d[(64 + h) * 65 + k]);
        int o = swz(h, k);
        WHp[o] = s.h; WLp[o] = s.l;
      }
      __syncthreads();
    }
    l1P[hf][0] = zero; l1P[hf][1] = zero;
    l1S[hf][0] = zero; l1S[hf][1] = zero;
#pragma unroll
    for (int kc = 0; kc < 2; kc++) {
      int ko = kc * 32 + quad * 8;
      f16x8 xh = *(const f16x8*)&AH[swz(nt * 16 + l15, ko)];
      f16x8 xl = *(const f16x8*)&AL[swz(nt * 16 + l15, ko)];
#pragma unroll
      for (int c2 = 0; c2 < 2; c2++) {
        int hr = (2 * wq + c2) * 16 + l15;
        f16x8 wh = *(const f16x8*)&WHp[swz(hr, ko)];
        f16x8 wl = *(const f16x8*)&WLp[swz(hr, ko)];
        l1P[hf][c2] = MFMA(wh, xh, l1P[hf][c2]);
        l1S[hf][c2] = MFMA(wl, xh, l1S[hf][c2]);
        l1S[hf][c2] = MFMA(wh, xl, l1S[hf][c2]);
      }
    }
  }
  __syncthreads();

  {
    int n = nt * 16 + l15;
#pragma unroll
    for (int hf = 0; hf < 2; hf++)
#pragma unroll
      for (int c2 = 0; c2 < 2; c2++) {
        int hb = hf * 64 + (2 * wq + c2) * 16 + quad * 4;
        f16x4 ah, al, dh, dl;
#pragma unroll
        for (int j = 0; j < 4; j++) {
          int h = hb + j;
          float w1j = W1d[h * 65 + 64];
          float p = l1P[hf][c2][j] + l1S[hf][c2][j] * INV2K + xtv * w1j + b1d[h];
          float s = p > 0.f ? 1.f : SLP;
          HL av = split(p * s), dv = split(s * w1j);
          ah[j] = av.h; al[j] = av.l; dh[j] = dv.h; dl[j] = dv.l;
        }
        int o = swz(n, hb);
        *(f16x4*)&AH[o] = ah; *(f16x4*)&AL[o] = al;
        *(f16x4*)&DH[o] = dh; *(f16x4*)&DL[o] = dl;
      }
  }
  stage_wf(WHp, WLp, W2 + d * Hh * Hh, tid);
  __syncthreads();

  f32x4 aP[2][2], aS[2][2], dP[2][2], dS[2][2];
  for (int hf = 0; hf < 2; hf++) {
    if (hf == 1) {
      __syncthreads();
      stage_wf(WHp, WLp, W2 + d * Hh * Hh + 64 * 128, tid);
      __syncthreads();
    }
    aP[hf][0] = zero; aP[hf][1] = zero; aS[hf][0] = zero; aS[hf][1] = zero;
    dP[hf][0] = zero; dP[hf][1] = zero; dS[hf][0] = zero; dS[hf][1] = zero;
    mid_mfma_half(AH, AL, DH, DL, WHp, WLp, nt, wq, l15, quad,
                  aP[hf], aS[hf], dP[hf], dS[hf]);
  }
  __syncthreads();

  {
    const float* b2d = b2 + d * Hh;
    int n = nt * 16 + l15;
#pragma unroll
    for (int hf = 0; hf < 2; hf++)
#pragma unroll
      for (int c2 = 0; c2 < 2; c2++) {
        int hb = hf * 64 + (2 * wq + c2) * 16 + quad * 4;
        f16x4 ah, al, dh, dl;
#pragma unroll
        for (int j = 0; j < 4; j++) {
          int h = hb + j;
          float p = aP[hf][c2][j] + aS[hf][c2][j] * INV2K + b2d[h];
          float s = p > 0.f ? 1.f : SLP;
          float dd = s * (dP[hf][c2][j] + dS[hf][c2][j] * INV2K);
          HL av = split(p * s), dv = split(dd);
          ah[j] = av.h; al[j] = av.l; dh[j] = dv.h; dl[j] = dv.l;
        }
        int o = swz(n, hb);
        *(f16x4*)&AH[o] = ah; *(f16x4*)&AL[o] = al;
        *(f16x4*)&DH[o] = dh; *(f16x4*)&DL[o] = dl;
      }
  }
  stage_wf(WHp, WLp, W3 + d * Hh * Hh, tid);
  __syncthreads();

  for (int hf = 0; hf < 2; hf++) {
    if (hf == 1) {
      __syncthreads();
      stage_wf(WHp, WLp, W3 + d * Hh * Hh + 64 * 128, tid);
      __syncthreads();
    }
    aP[hf][0] = zero; aP[hf][1] = zero; aS[hf][0] = zero; aS[hf][1] = zero;
    dP[hf][0] = zero; dP[hf][1] = zero; dS[hf][0] = zero; dS[hf][1] = zero;
    mid_mfma_half(AH, AL, DH, DL, WHp, WLp, nt, wq, l15, quad,
                  aP[hf], aS[hf], dP[hf], dS[hf]);
  }
  __syncthreads();

  {
    const float* b3d = b3 + d * Hh;
    int n = nt * 16 + l15;
#pragma unroll
    for (int hf = 0; hf < 2; hf++)
#pragma unroll
      for (int c2 = 0; c2 < 2; c2++) {
        int hb = hf * 64 + (2 * wq + c2) * 16 + quad * 4;
        float4 pa, pd;
#pragma unroll
        for (int j = 0; j < 4; j++) {
          int h = hb + j;
          float p = aP[hf][c2][j] + aS[hf][c2][j] * INV2K + b3d[h];
          float s = p > 0.f ? 1.f : SLP;
          (&pa.x)[j] = p * s;
          (&pd.x)[j] = s * (dP[hf][c2][j] + dS[hf][c2][j] * INV2K);
        }
        *(float4*)&A3F[swzF(n, hb)] = pa;
        *(float4*)&D3F[swzF(n, hb)] = pd;
      }
  }
  __syncthreads();

  {
    int n = tid >> 3, oct = tid & 7;
    const float* w4d = W4 + d * Hh;
    float sr = 0.f, sd = 0.f;
#pragma unroll
    for (int i = 0; i < 4; i++) {
      int c = oct * 16 + i * 4;
      float4 va = *(const float4*)&A3F[swzF(n, c)];
      float4 vd = *(const float4*)&D3F[swzF(n, c)];
      float4 w = *(const float4*)&w4d[c];
      sr += va.x * w.x + va.y * w.y + va.z * w.z + va.w * w.w;
      sd += vd.x * w.x + vd.y * w.y + vd.z * w.z + vd.w * w.w;
    }
    sr += __shfl_xor(sr, 1); sr += __shfl_xor(sr, 2); sr += __shfl_xor(sr, 4);
    sd += __shfl_xor(sd, 1); sd += __shfl_xor(sd, 2); sd += __shfl_xor(sd, 4);
    if (oct == 0) {
      int ng = n0 + n;
      out_res[ng * 64 + d] = sr + b4[d];
      atomicAdd(&out_log[ng], logf(fabsf(sd) + 1e-8f));
    }
  }
}

extern "C" void kernel_launch(void* const* d_in, const int* in_sizes, int n_in,
                              void* d_out, int out_size, void* d_ws, size_t ws_size,
                              hipStream_t stream) {
  (void)in_sizes; (void)n_in; (void)out_size;
  const float* x  = (const float*)d_in[0];
  const float* W1 = (const float*)d_in[1];
  const float* b1 = (const float*)d_in[2];
  const float* W2 = (const float*)d_in[3];
  const float* b2 = (const float*)d_in[4];
  const float* W3 = (const float*)d_in[5];
  const float* b3 = (const float*)d_in[6];
  const float* W4 = (const float*)d_in[7];
  const float* b4 = (const float*)d_in[8];

  float* out_res = (float*)d_out;
  float* out_log = out_res + Nn * Dd;

  dim3 grid(Nn / NT, Dd);
  if (ws_size >= WS_NEEDED) {
    f16* wsf = (f16*)d_ws;
    float* w1lg = (float*)((char*)d_ws + W1L_OFF);
    // prep also zeroes out_log -> no separate memset dispatch
    prep_kernel<<<dim3(Dd, 5), 256, 0, stream>>>(W1, W2, W3, wsf, w1lg, out_log);
    np_prior_fast<<<grid, 512, 0, stream>>>(x, wsf, w1lg, b1, b2, b3, W4, b4,
                                            out_res, out_log);
  } else {
    hipMemsetAsync(out_log, 0, Nn * sizeof(float), stream);
    np_prior_fb<<<grid, 256, 0, stream>>>(x, W1, b1, W2, b2, W3, b3, W4, b4,
                                          out_res, out_log);
  }
}

// Round 6
// 244.899 us; speedup vs baseline: 1.1708x; 1.0128x over previous
//
#include <hip/hip_runtime.h>
#include <hip/hip_bf16.h>
#include <math.h>

typedef _Float16 f16;
typedef _Float16 f16x8 __attribute__((ext_vector_type(8)));
typedef _Float16 f16x4 __attribute__((ext_vector_type(4)));
typedef _Float16 f16x2 __attribute__((ext_vector_type(2)));
typedef float f32x4 __attribute__((ext_vector_type(4)));

#define MFMA(a, b, c) __builtin_amdgcn_mfma_f32_16x16x32_f16((a), (b), (c), 0, 0, 0)

constexpr int Dd = 64;
constexpr int Hh = 128;
constexpr int Nn = 4096;
constexpr int NT = 32;
constexpr float SLP = 0.2f;
constexpr float INV2K = 1.0f / 2048.0f;

// Per-d f16 layout in d_ws (preprocessed, pre-swizzled, hi/lo split):
//   [0,8192)      W1 half0: hi 4096 | lo 4096   (compact K=64 swizzle)
//   [8192,16384)  W1 half1
//   [16384,49152) W2: h0 (hi 8192 | lo 8192), h1
//   [49152,81920) W3: h0, h1
constexpr int PD = 81920;
constexpr size_t W1L_OFF = (size_t)Dd * PD * 2;  // bytes; then w1last f32[64][128]
constexpr size_t WS_NEEDED = W1L_OFF + (size_t)Dd * Hh * 4;

// XOR swizzle, [r][128] f16, 8-elem chunks, chunk ^= r&15 (2-way max = free)
__device__ __forceinline__ int swz(int r, int c) {
  return (r << 7) + ((((c >> 3) ^ (r & 15)) << 3) | (c & 7));
}
// Compact K=64 swizzle, [r][64] f16, chunk ^= r&7
__device__ __forceinline__ int swzK64(int r, int c) {
  return (r << 6) + (((((c >> 3) ^ r) & 7) << 3) | (c & 7));
}
// f32 overlay swizzle, [n][128] f32, 4-elem chunks
__device__ __forceinline__ int swzF(int n, int h) {
  return (n << 7) + ((((h >> 2) ^ n) & 31) << 2) + (h & 3);
}

struct HL { f16 h, l; };
__device__ __forceinline__ HL split(float v) {
  HL r;
  r.h = (f16)v;
  r.l = (f16)((v - (float)r.h) * 2048.0f);
  return r;
}

// Async contiguous global->LDS, 512 threads: nbytes multiple of 8192
__device__ __forceinline__ void cp_lds_async512(const void* g, void* l, int nbytes, int tid) {
  const int lane = tid & 63, wv = tid >> 6;
  for (int base = wv * 1024; base < nbytes; base += 8192) {
    __builtin_amdgcn_global_load_lds(
        (const __attribute__((address_space(1))) void*)((const char*)g + base + lane * 16),
        (__attribute__((address_space(3))) void*)((char*)l + base), 16, 0, 0);
  }
}

// ---------------- preprocess v2: fully coalesced via LDS ---------------------
// Global reads: float4, linear per wave. Global writes: f16x8, linear per wave.
// The swizzle permutation is absorbed by the LDS *read* position.
__global__ __launch_bounds__(256)
void prep_kernel(const float* __restrict__ W1, const float* __restrict__ W2,
                 const float* __restrict__ W3, f16* __restrict__ wsf,
                 float* __restrict__ w1lg, float* __restrict__ out_log) {
  __shared__ float lds[64 * 132];  // 33.8 KB (W1 path uses flat 8320 floats)
  const int d = blockIdx.x, sec = blockIdx.y, tid = threadIdx.x;
  f16* out = wsf + (size_t)d * PD;

  if (sec == 0) {
    // ---- W1: input [128][65] f32 contiguous (8320 floats) -> flat LDS
    const float* W1d = W1 + d * Hh * 65;
    const float4* g4 = (const float4*)W1d;  // d*8320*4 bytes, 16B-aligned
    for (int i = tid; i < 2080; i += 256) ((float4*)lds)[i] = g4[i];
    __syncthreads();
    // output: 2048 linear 16B chunks over W1 region [0,16384) f16
    // ci = hf*1024 + plane*512 + j ; j = r*8 + sc ; src chunk = sc ^ (r&7)
    for (int ci = tid; ci < 2048; ci += 256) {
      int hf = ci >> 10, rem = ci & 1023;
      int plane = rem >> 9, j = rem & 511;  // 0=hi, 1=lo
      int r = j >> 3, sc = j & 7;
      int h = hf * 64 + r;
      int k0 = (sc ^ (r & 7)) << 3;
      const float* src = &lds[h * 65 + k0];
      f16x8 v;
#pragma unroll
      for (int e = 0; e < 8; e++) {
        float f = src[e];
        if (plane == 0) v[e] = (f16)f;
        else {
          f16 hi = (f16)f;
          v[e] = (f16)((f - (float)hi) * 2048.0f);
        }
      }
      *(f16x8*)&out[ci * 8] = v;  // linear, coalesced
    }
    if (tid < 128) w1lg[d * Hh + tid] = lds[tid * 65 + 64];
    if (tid < 64) out_log[d * 64 + tid] = 0.f;  // 64 blocks x 64 = 4096
  } else {
    // ---- W2/W3 half: input 64x128 f32 -> padded LDS rows (stride 132)
    int w = (sec - 1) >> 1, hh = (sec - 1) & 1;  // w: 0=W2 1=W3
    const float* g = (w == 0 ? W2 : W3) + d * Hh * Hh + hh * 8192;
    const float4* g4 = (const float4*)g;
    for (int i = tid; i < 2048; i += 256) {
      int r = i >> 5, c4 = (i & 31) << 2;
      *(float4*)&lds[r * 132 + c4] = g4[i];
    }
    __syncthreads();
    // output: 2048 linear chunks over [hi 8192 | lo 8192] f16
    f16* ob = out + 16384 + w * 32768 + hh * 16384;
    for (int ci = tid; ci < 2048; ci += 256) {
      int plane = ci >> 10, j = ci & 1023;
      int r = j >> 4, sc = j & 15;
      int k0 = (sc ^ (r & 15)) << 3;
      const float* src = &lds[r * 132 + k0];
      f16x8 v;
#pragma unroll
      for (int e = 0; e < 8; e++) {
        float f = src[e];
        if (plane == 0) v[e] = (f16)f;
        else {
          f16 hi = (f16)f;
          v[e] = (f16)((f - (float)hi) * 2048.0f);
        }
      }
      *(f16x8*)&ob[ci * 8] = v;  // linear, coalesced
    }
  }
}

// One W-half of a mid layer, one h-tile per wave. All operands from LDS.
__device__ __forceinline__ void mid_half(
    const f16* AH, const f16* AL, const f16* DH, const f16* DL,
    const f16* WH, const f16* WL, int ra, int hr, int quad,
    f32x4& aP, f32x4& aS, f32x4& dP, f32x4& dS) {
#pragma unroll
  for (int kc = 0; kc < 4; kc++) {
    int ko = kc * 32 + quad * 8;
    f16x8 xh = *(const f16x8*)&AH[swz(ra, ko)];
    f16x8 xl = *(const f16x8*)&AL[swz(ra, ko)];
    f16x8 yh = *(const f16x8*)&DH[swz(ra, ko)];
    f16x8 yl = *(const f16x8*)&DL[swz(ra, ko)];
    f16x8 wh = *(const f16x8*)&WH[swz(hr, ko)];
    f16x8 wl = *(const f16x8*)&WL[swz(hr, ko)];
    aP = MFMA(wh, xh, aP);
    aS = MFMA(wl, xh, aS);
    aS = MFMA(wh, xl, aS);
    dP = MFMA(wh, yh, dP);
    dS = MFMA(wl, yh, dS);
    dS = MFMA(wh, yl, dS);
  }
}

// 512 threads (8 waves): nt = wv&1 picks the 16-sample tile, wq = wv>>1 picks
// the h-tile within the staged 64-row W half. 64 KB LDS -> 2 blocks/CU ->
// 16 waves/CU (4/SIMD).   [UNCHANGED from R5 for attribution]
__global__ __launch_bounds__(512, 4)
void np_prior_fast(const float* __restrict__ x, const f16* __restrict__ wsw,
                   const float* __restrict__ w1lg,
                   const float* __restrict__ b1, const float* __restrict__ b2,
                   const float* __restrict__ b3, const float* __restrict__ W4,
                   const float* __restrict__ b4,
                   float* __restrict__ out_res, float* __restrict__ out_log) {
  __shared__ float4 smem[4096];  // 64 KB
  f16* AH = (f16*)smem;                     // [32][128] 8 KB each plane
  f16* AL = AH + NT * 128;
  f16* DH = AL + NT * 128;
  f16* DL = DH + NT * 128;
  f16* Wreg = (f16*)((char*)smem + 32768);  // 32 KB W staging (hi | lo)
  float* A3F = (float*)smem;                // f32 overlay (swzF), 16 KB
  float* D3F = (float*)((char*)smem + 16384);

  const int tid = threadIdx.x, d = blockIdx.y, n0 = blockIdx.x * NT;
  const int lane = tid & 63, wv = tid >> 6, l15 = lane & 15, quad = lane >> 4;
  const int nt = wv & 1, wq = wv >> 1;
  const int ra = nt * 16 + l15;
  const int hr = wq * 16 + l15;

  const f16* wd = wsw + (size_t)d * PD;
  const float* w1l = w1lg + d * Hh;
  const float* b1d = b1 + d * Hh;
  const f32x4 zero = {0.f, 0.f, 0.f, 0.f};

  cp_lds_async512(wd, Wreg, 16384, tid);
  {
    int n = tid >> 4, k4 = (tid & 15) << 2;
    int ng = n0 + n, bb = ng >> 8, tt = ng & 255;
    float4 v = *(const float4*)&x[(bb * 257 + tt) * 64 + k4];
    HL a = split(v.x), b = split(v.y), c = split(v.z), e = split(v.w);
    int o = swz(n, k4);
    *(f16x4*)&AH[o] = f16x4{a.h, b.h, c.h, e.h};
    *(f16x4*)&AL[o] = f16x4{a.l, b.l, c.l, e.l};
  }
  float xtv;
  {
    int ng = n0 + ra, bb = ng >> 8, tt = ng & 255;
    xtv = x[(bb * 257 + tt + 1) * 64 + d];
  }
  __syncthreads();

  // ---- Layer 1 (K=64)
  f32x4 l1P[2], l1S[2];
#pragma unroll
  for (int hf = 0; hf < 2; hf++) {
    if (hf == 1) {
      __syncthreads();
      cp_lds_async512(wd + 8192, Wreg, 16384, tid);
      __syncthreads();
    }
    l1P[hf] = zero; l1S[hf] = zero;
#pragma unroll
    for (int kc = 0; kc < 2; kc++) {
      int ko = kc * 32 + quad * 8;
      f16x8 xh = *(const f16x8*)&AH[swz(ra, ko)];
      f16x8 xl = *(const f16x8*)&AL[swz(ra, ko)];
      f16x8 wh = *(const f16x8*)&Wreg[swzK64(hr, ko)];
      f16x8 wl = *(const f16x8*)&Wreg[4096 + swzK64(hr, ko)];
      l1P[hf] = MFMA(wh, xh, l1P[hf]);
      l1S[hf] = MFMA(wl, xh, l1S[hf]);
      l1S[hf] = MFMA(wh, xl, l1S[hf]);
    }
  }
  __syncthreads();
  cp_lds_async512(wd + 16384, Wreg, 32768, tid);  // W2-h0

  // ---- L1 epilogue
#pragma unroll
  for (int hf = 0; hf < 2; hf++) {
    int hb = hf * 64 + wq * 16 + quad * 4;
    float4 wv4 = *(const float4*)&w1l[hb];
    float4 bv4 = *(const float4*)&b1d[hb];
    f16x4 ah, al, dh, dl;
#pragma unroll
    for (int j = 0; j < 4; j++) {
      float w1j = (&wv4.x)[j];
      float p = l1P[hf][j] + l1S[hf][j] * INV2K + xtv * w1j + (&bv4.x)[j];
      float s = p > 0.f ? 1.f : SLP;
      HL av = split(p * s), dv = split(s * w1j);
      ah[j] = av.h; al[j] = av.l; dh[j] = dv.h; dl[j] = dv.l;
    }
    int o = swz(ra, hb);
    *(f16x4*)&AH[o] = ah; *(f16x4*)&AL[o] = al;
    *(f16x4*)&DH[o] = dh; *(f16x4*)&DL[o] = dl;
  }
  __syncthreads();

  // ---- Layer 2
  f32x4 aP[2], aS[2], dP[2], dS[2];
#pragma unroll
  for (int hf = 0; hf < 2; hf++) {
    if (hf == 1) {
      __syncthreads();
      cp_lds_async512(wd + 32768, Wreg, 32768, tid);  // W2-h1
      __syncthreads();
    }
    aP[hf] = zero; aS[hf] = zero; dP[hf] = zero; dS[hf] = zero;
    mid_half(AH, AL, DH, DL, Wreg, Wreg + 8192, ra, hr, quad,
             aP[hf], aS[hf], dP[hf], dS[hf]);
  }
  __syncthreads();
  cp_lds_async512(wd + 49152, Wreg, 32768, tid);  // W3-h0

  // ---- L2 epilogue
  {
    const float* b2d = b2 + d * Hh;
#pragma unroll
    for (int hf = 0; hf < 2; hf++) {
      int hb = hf * 64 + wq * 16 + quad * 4;
      float4 bv4 = *(const float4*)&b2d[hb];
      f16x4 ah, al, dh, dl;
#pragma unroll
      for (int j = 0; j < 4; j++) {
        float p = aP[hf][j] + aS[hf][j] * INV2K + (&bv4.x)[j];
        float s = p > 0.f ? 1.f : SLP;
        float dd = s * (dP[hf][j] + dS[hf][j] * INV2K);
        HL av = split(p * s), dv = split(dd);
        ah[j] = av.h; al[j] = av.l; dh[j] = dv.h; dl[j] = dv.l;
      }
      int o = swz(ra, hb);
      *(f16x4*)&AH[o] = ah; *(f16x4*)&AL[o] = al;
      *(f16x4*)&DH[o] = dh; *(f16x4*)&DL[o] = dl;
    }
  }
  __syncthreads();

  // ---- Layer 3
#pragma unroll
  for (int hf = 0; hf < 2; hf++) {
    if (hf == 1) {
      __syncthreads();
      cp_lds_async512(wd + 65536, Wreg, 32768, tid);  // W3-h1
      __syncthreads();
    }
    aP[hf] = zero; aS[hf] = zero; dP[hf] = zero; dS[hf] = zero;
    mid_half(AH, AL, DH, DL, Wreg, Wreg + 8192, ra, hr, quad,
             aP[hf], aS[hf], dP[hf], dS[hf]);
  }
  __syncthreads();

  // ---- L3 epilogue -> swizzled f32 overlay
  {
    const float* b3d = b3 + d * Hh;
#pragma unroll
    for (int hf = 0; hf < 2; hf++) {
      int hb = hf * 64 + wq * 16 + quad * 4;
      float4 bv4 = *(const float4*)&b3d[hb];
      float4 pa, pd;
#pragma unroll
      for (int j = 0; j < 4; j++) {
        float p = aP[hf][j] + aS[hf][j] * INV2K + (&bv4.x)[j];
        float s = p > 0.f ? 1.f : SLP;
        (&pa.x)[j] = p * s;
        (&pd.x)[j] = s * (dP[hf][j] + dS[hf][j] * INV2K);
      }
      *(float4*)&A3F[swzF(ra, hb)] = pa;
      *(float4*)&D3F[swzF(ra, hb)] = pd;
    }
  }
  __syncthreads();

  // ---- Layer 4
  {
    int n = tid >> 4, g16 = tid & 15;
    const float* w4d = W4 + d * Hh;
    int c = g16 * 8;
    float4 va0 = *(const float4*)&A3F[swzF(n, c)];
    float4 va1 = *(const float4*)&A3F[swzF(n, c + 4)];
    float4 vd0 = *(const float4*)&D3F[swzF(n, c)];
    float4 vd1 = *(const float4*)&D3F[swzF(n, c + 4)];
    float4 w0 = *(const float4*)&w4d[c];
    float4 w1 = *(const float4*)&w4d[c + 4];
    float sr = va0.x * w0.x + va0.y * w0.y + va0.z * w0.z + va0.w * w0.w +
               va1.x * w1.x + va1.y * w1.y + va1.z * w1.z + va1.w * w1.w;
    float sd = vd0.x * w0.x + vd0.y * w0.y + vd0.z * w0.z + vd0.w * w0.w +
               vd1.x * w1.x + vd1.y * w1.y + vd1.z * w1.z + vd1.w * w1.w;
    sr += __shfl_xor(sr, 1); sr += __shfl_xor(sr, 2);
    sr += __shfl_xor(sr, 4); sr += __shfl_xor(sr, 8);
    sd += __shfl_xor(sd, 1); sd += __shfl_xor(sd, 2);
    sd += __shfl_xor(sd, 4); sd += __shfl_xor(sd, 8);
    if (g16 == 0) {
      int ng = n0 + n;
      out_res[ng * 64 + d] = sr + b4[d];
      atomicAdd(&out_log[ng], logf(fabsf(sd) + 1e-8f));
    }
  }
}

// ---------------- fallback (no-ws path, 256 threads) -------------------------
__device__ __forceinline__ void stage_wf(f16* WH, f16* WL,
                                         const float* __restrict__ g, int tid) {
  for (int i = tid; i < 2048; i += 256) {
    int h = i >> 5, k4 = (i & 31) << 2;
    float4 v = ((const float4*)g)[i];
    HL a = split(v.x), b = split(v.y), c = split(v.z), e = split(v.w);
    int o = swz(h, k4);
    *(f16x4*)&WH[o] = f16x4{a.h, b.h, c.h, e.h};
    *(f16x4*)&WL[o] = f16x4{a.l, b.l, c.l, e.l};
  }
}

__device__ __forceinline__ void mid_mfma_half(
    const f16* AH, const f16* AL, const f16* DH, const f16* DL,
    const f16* WH, const f16* WL, int nt, int wq, int l15, int quad,
    f32x4* aP, f32x4* aS, f32x4* dP, f32x4* dS) {
#pragma unroll
  for (int kc = 0; kc < 4; kc++) {
    int ko = kc * 32 + quad * 8;
    int ra = nt * 16 + l15;
    f16x8 xh = *(const f16x8*)&AH[swz(ra, ko)];
    f16x8 xl = *(const f16x8*)&AL[swz(ra, ko)];
    f16x8 yh = *(const f16x8*)&DH[swz(ra, ko)];
    f16x8 yl = *(const f16x8*)&DL[swz(ra, ko)];
#pragma unroll
    for (int c2 = 0; c2 < 2; c2++) {
      int hr = (2 * wq + c2) * 16 + l15;
      f16x8 wh = *(const f16x8*)&WH[swz(hr, ko)];
      f16x8 wl = *(const f16x8*)&WL[swz(hr, ko)];
      aP[c2] = MFMA(wh, xh, aP[c2]);
      aS[c2] = MFMA(wl, xh, aS[c2]);
      aS[c2] = MFMA(wh, xl, aS[c2]);
      dP[c2] = MFMA(wh, yh, dP[c2]);
      dS[c2] = MFMA(wl, yh, dS[c2]);
      dS[c2] = MFMA(wh, yl, dS[c2]);
    }
  }
}

__global__ __launch_bounds__(256, 2)
void np_prior_fb(const float* __restrict__ x,
                 const float* __restrict__ W1, const float* __restrict__ b1,
                 const float* __restrict__ W2, const float* __restrict__ b2,
                 const float* __restrict__ W3, const float* __restrict__ b3,
                 const float* __restrict__ W4, const float* __restrict__ b4,
                 float* __restrict__ out_res, float* __restrict__ out_log) {
  __shared__ float4 smem[4096];
  f16* AH = (f16*)smem;
  f16* AL = AH + NT * 128;
  f16* DH = AL + NT * 128;
  f16* DL = DH + NT * 128;
  f16* WHp = (f16*)((char*)smem + 32768);
  f16* WLp = WHp + 64 * 128;
  float* A3F = (float*)smem;
  float* D3F = (float*)((char*)smem + 16384);

  const int tid = threadIdx.x, d = blockIdx.y, n0 = blockIdx.x * NT;
  const int lane = tid & 63, wv = tid >> 6, l15 = lane & 15, quad = lane >> 4;
  const int nt = wv & 1, wq = wv >> 1;

  const float* W1d = W1 + d * Hh * 65;
  const float* b1d = b1 + d * Hh;
  const f32x4 zero = {0.f, 0.f, 0.f, 0.f};

  for (int i = tid; i < NT * 16; i += 256) {
    int n = i >> 4, k4 = (i & 15) << 2;
    int ng = n0 + n, bb = ng >> 8, tt = ng & 255;
    float4 v = *(const float4*)&x[(bb * 257 + tt) * 64 + k4];
    HL a = split(v.x), b = split(v.y), c = split(v.z), e = split(v.w);
    int o = swz(n, k4);
    *(f16x4*)&AH[o] = f16x4{a.h, b.h, c.h, e.h};
    *(f16x4*)&AL[o] = f16x4{a.l, b.l, c.l, e.l};
  }
  float xtv;
  {
    int ng = n0 + nt * 16 + l15, bb = ng >> 8, tt = ng & 255;
    xtv = x[(bb * 257 + tt + 1) * 64 + d];
  }
  for (int i = tid; i < 64 * 64; i += 256) {
    int h = i >> 6, k = i & 63;
    HL s = split(W1d[h * 65 + k]);
    int o = swz(h, k);
    WHp[o] = s.h; WLp[o] = s.l;
  }
  __syncthreads();

  f32x4 l1P[2][2], l1S[2][2];
  for (int hf = 0; hf < 2; hf++) {
    if (hf == 1) {
      __syncthreads();
      for (int i = tid; i < 64 * 64; i += 256) {
        int h = i >> 6, k = i & 63;
        HL s = split(W1d[(64 + h) * 65 + k]);
        int o = swz(h, k);
        WHp[o] = s.h; WLp[o] = s.l;
      }
      __syncthreads();
    }
    l1P[hf][0] = zero; l1P[hf][1] = zero;
    l1S[hf][0] = zero; l1S[hf][1] = zero;
#pragma unroll
    for (int kc = 0; kc < 2; kc++) {
      int ko = kc * 32 + quad * 8;
      f16x8 xh = *(const f16x8*)&AH[swz(nt * 16 + l15, ko)];
      f16x8 xl = *(const f16x8*)&AL[swz(nt * 16 + l15, ko)];
#pragma unroll
      for (int c2 = 0; c2 < 2; c2++) {
        int hr = (2 * wq + c2) * 16 + l15;
        f16x8 wh = *(const f16x8*)&WHp[swz(hr, ko)];
        f16x8 wl = *(const f16x8*)&WLp[swz(hr, ko)];
        l1P[hf][c2] = MFMA(wh, xh, l1P[hf][c2]);
        l1S[hf][c2] = MFMA(wl, xh, l1S[hf][c2]);
        l1S[hf][c2] = MFMA(wh, xl, l1S[hf][c2]);
      }
    }
  }
  __syncthreads();

  {
    int n = nt * 16 + l15;
#pragma unroll
    for (int hf = 0; hf < 2; hf++)
#pragma unroll
      for (int c2 = 0; c2 < 2; c2++) {
        int hb = hf * 64 + (2 * wq + c2) * 16 + quad * 4;
        f16x4 ah, al, dh, dl;
#pragma unroll
        for (int j = 0; j < 4; j++) {
          int h = hb + j;
          float w1j = W1d[h * 65 + 64];
          float p = l1P[hf][c2][j] + l1S[hf][c2][j] * INV2K + xtv * w1j + b1d[h];
          float s = p > 0.f ? 1.f : SLP;
          HL av = split(p * s), dv = split(s * w1j);
          ah[j] = av.h; al[j] = av.l; dh[j] = dv.h; dl[j] = dv.l;
        }
        int o = swz(n, hb);
        *(f16x4*)&AH[o] = ah; *(f16x4*)&AL[o] = al;
        *(f16x4*)&DH[o] = dh; *(f16x4*)&DL[o] = dl;
      }
  }
  stage_wf(WHp, WLp, W2 + d * Hh * Hh, tid);
  __syncthreads();

  f32x4 aP[2][2], aS[2][2], dP[2][2], dS[2][2];
  for (int hf = 0; hf < 2; hf++) {
    if (hf == 1) {
      __syncthreads();
      stage_wf(WHp, WLp, W2 + d * Hh * Hh + 64 * 128, tid);
      __syncthreads();
    }
    aP[hf][0] = zero; aP[hf][1] = zero; aS[hf][0] = zero; aS[hf][1] = zero;
    dP[hf][0] = zero; dP[hf][1] = zero; dS[hf][0] = zero; dS[hf][1] = zero;
    mid_mfma_half(AH, AL, DH, DL, WHp, WLp, nt, wq, l15, quad,
                  aP[hf], aS[hf], dP[hf], dS[hf]);
  }
  __syncthreads();

  {
    const float* b2d = b2 + d * Hh;
    int n = nt * 16 + l15;
#pragma unroll
    for (int hf = 0; hf < 2; hf++)
#pragma unroll
      for (int c2 = 0; c2 < 2; c2++) {
        int hb = hf * 64 + (2 * wq + c2) * 16 + quad * 4;
        f16x4 ah, al, dh, dl;
#pragma unroll
        for (int j = 0; j < 4; j++) {
          int h = hb + j;
          float p = aP[hf][c2][j] + aS[hf][c2][j] * INV2K + b2d[h];
          float s = p > 0.f ? 1.f : SLP;
          float dd = s * (dP[hf][c2][j] + dS[hf][c2][j] * INV2K);
          HL av = split(p * s), dv = split(dd);
          ah[j] = av.h; al[j] = av.l; dh[j] = dv.h; dl[j] = dv.l;
        }
        int o = swz(n, hb);
        *(f16x4*)&AH[o] = ah; *(f16x4*)&AL[o] = al;
        *(f16x4*)&DH[o] = dh; *(f16x4*)&DL[o] = dl;
      }
  }
  stage_wf(WHp, WLp, W3 + d * Hh * Hh, tid);
  __syncthreads();

  for (int hf = 0; hf < 2; hf++) {
    if (hf == 1) {
      __syncthreads();
      stage_wf(WHp, WLp, W3 + d * Hh * Hh + 64 * 128, tid);
      __syncthreads();
    }
    aP[hf][0] = zero; aP[hf][1] = zero; aS[hf][0] = zero; aS[hf][1] = zero;
    dP[hf][0] = zero; dP[hf][1] = zero; dS[hf][0] = zero; dS[hf][1] = zero;
    mid_mfma_half(AH, AL, DH, DL, WHp, WLp, nt, wq, l15, quad,
                  aP[hf], aS[hf], dP[hf], dS[hf]);
  }
  __syncthreads();

  {
    const float* b3d = b3 + d * Hh;
    int n = nt * 16 + l15;
#pragma unroll
    for (int hf = 0; hf < 2; hf++)
#pragma unroll
      for (int c2 = 0; c2 < 2; c2++) {
        int hb = hf * 64 + (2 * wq + c2) * 16 + quad * 4;
        float4 pa, pd;
#pragma unroll
        for (int j = 0; j < 4; j++) {
          int h = hb + j;
          float p = aP[hf][c2][j] + aS[hf][c2][j] * INV2K + b3d[h];
          float s = p > 0.f ? 1.f : SLP;
          (&pa.x)[j] = p * s;
          (&pd.x)[j] = s * (dP[hf][c2][j] + dS[hf][c2][j] * INV2K);
        }
        *(float4*)&A3F[swzF(n, hb)] = pa;
        *(float4*)&D3F[swzF(n, hb)] = pd;
      }
  }
  __syncthreads();

  {
    int n = tid >> 3, oct = tid & 7;
    const float* w4d = W4 + d * Hh;
    float sr = 0.f, sd = 0.f;
#pragma unroll
    for (int i = 0; i < 4; i++) {
      int c = oct * 16 + i * 4;
      float4 va = *(const float4*)&A3F[swzF(n, c)];
      float4 vd = *(const float4*)&D3F[swzF(n, c)];
      float4 w = *(const float4*)&w4d[c];
      sr += va.x * w.x + va.y * w.y + va.z * w.z + va.w * w.w;
      sd += vd.x * w.x + vd.y * w.y + vd.z * w.z + vd.w * w.w;
    }
    sr += __shfl_xor(sr, 1); sr += __shfl_xor(sr, 2); sr += __shfl_xor(sr, 4);
    sd += __shfl_xor(sd, 1); sd += __shfl_xor(sd, 2); sd += __shfl_xor(sd, 4);
    if (oct == 0) {
      int ng = n0 + n;
      out_res[ng * 64 + d] = sr + b4[d];
      atomicAdd(&out_log[ng], logf(fabsf(sd) + 1e-8f));
    }
  }
}

extern "C" void kernel_launch(void* const* d_in, const int* in_sizes, int n_in,
                              void* d_out, int out_size, void* d_ws, size_t ws_size,
                              hipStream_t stream) {
  (void)in_sizes; (void)n_in; (void)out_size;
  const float* x  = (const float*)d_in[0];
  const float* W1 = (const float*)d_in[1];
  const float* b1 = (const float*)d_in[2];
  const float* W2 = (const float*)d_in[3];
  const float* b2 = (const float*)d_in[4];
  const float* W3 = (const float*)d_in[5];
  const float* b3 = (const float*)d_in[6];
  const float* W4 = (const float*)d_in[7];
  const float* b4 = (const float*)d_in[8];

  float* out_res = (float*)d_out;
  float* out_log = out_res + Nn * Dd;

  dim3 grid(Nn / NT, Dd);
  if (ws_size >= WS_NEEDED) {
    f16* wsf = (f16*)d_ws;
    float* w1lg = (float*)((char*)d_ws + W1L_OFF);
    prep_kernel<<<dim3(Dd, 5), 256, 0, stream>>>(W1, W2, W3, wsf, w1lg, out_log);
    np_prior_fast<<<grid, 512, 0, stream>>>(x, wsf, w1lg, b1, b2, b3, W4, b4,
                                            out_res, out_log);
  } else {
    hipMemsetAsync(out_log, 0, Nn * sizeof(float), stream);
    np_prior_fb<<<grid, 256, 0, stream>>>(x, W1, b1, W2, b2, W3, b3, W4, b4,
                                          out_res, out_log);
  }
}